// Round 12
// baseline (1748.585 us; speedup 1.0000x reference)
//
#include <hip/hip_runtime.h>
#include <hip/hip_bf16.h>
#include <stdint.h>

#define BATCH 2048
#define FDIM 512
#define CDIM 64

typedef unsigned short ushort_t;
typedef __attribute__((ext_vector_type(8))) short short8;
typedef __attribute__((ext_vector_type(4))) float f32x4;

__device__ __forceinline__ ushort_t f2bf(float x) {
    union { float f; uint32_t u; } v; v.f = x;
    uint32_t u = v.u;
    uint32_t r = u + 0x7FFFu + ((u >> 16) & 1u);  // round-to-nearest-even
    return (ushort_t)(r >> 16);
}
__device__ __forceinline__ float bf2f(ushort_t u) {
    union { float f; uint32_t v; } x; x.v = ((uint32_t)u) << 16; return x.f;
}

// ---- fused fp32->bf16 convert: W_proj (8192 blocks), f_feat (512), t_feat (512) ----
__global__ void convert_all_kernel(const float* __restrict__ W, ushort_t* __restrict__ Wb,
                                   const float* __restrict__ f, ushort_t* __restrict__ f16,
                                   const float* __restrict__ t, ushort_t* __restrict__ t16) {
    int blk = blockIdx.x;
    const float* src; ushort_t* dst; int idx;
    if (blk < 8192)      { src = W; dst = Wb;  idx = blk * 256 + threadIdx.x; }
    else if (blk < 8704) { src = f; dst = f16; idx = (blk - 8192) * 256 + threadIdx.x; }
    else                 { src = t; dst = t16; idx = (blk - 8704) * 256 + threadIdx.x; }
    float4 v0 = ((const float4*)src)[idx * 2];
    float4 v1 = ((const float4*)src)[idx * 2 + 1];
    ushort_t p[8] = { f2bf(v0.x), f2bf(v0.y), f2bf(v0.z), f2bf(v0.w),
                      f2bf(v1.x), f2bf(v1.y), f2bf(v1.z), f2bf(v1.w) };
    *(uint4*)&dst[idx * 8] = *(uint4*)p;
}

#define AS3(p) ((__attribute__((address_space(3))) void*)(p))
#define AS1(p) ((const __attribute__((address_space(1))) void*)(p))

// ---- 256x256 tile, BK=32, SINGLE-buffered LDS, 512-thread blocks -> 4 blocks/CU.
// Schedule per K-step: STAGE -> __syncthreads -> COMPUTE -> __syncthreads (provably
// race-free). The drain's latency is covered by the 3 OTHER resident blocks' compute
// (cross-block TLP, the m97/m114 mechanism) instead of own-compute prefetch distance.
// 8 waves = 4m x 2n; each wave computes 64 x 128 (acc 128 VGPR).
// u[b,n] = sum_j f16[b,j]*Wb[n,j]; n = c*512+i; epilogue contracts with t16[b,i].

#define STAGE(kt)                                                                   \
    { _Pragma("unroll")                                                             \
      for (int l = 0; l < 2; l++) {                                                 \
        __builtin_amdgcn_global_load_lds(AS1(gA[l] + (kt) * 32),                    \
            AS3(&As[l * 4096 + wave * 512]), 16, 0, 0);                             \
        __builtin_amdgcn_global_load_lds(AS1(gB[l] + (kt) * 32),                    \
            AS3(&Bs[l * 4096 + wave * 512]), 16, 0, 0);                             \
      } }

#define COMPUTE()                                                                   \
    { short8 a[4], b[8];                                                            \
      _Pragma("unroll")                                                             \
      for (int mi = 0; mi < 4; mi++) a[mi] = *(const short8*)&As[a_off[mi]];        \
      _Pragma("unroll")                                                             \
      for (int ni = 0; ni < 8; ni++) b[ni] = *(const short8*)&Bs[b_off[ni]];        \
      _Pragma("unroll")                                                             \
      for (int mi = 0; mi < 4; mi++) {                                              \
        _Pragma("unroll")                                                           \
        for (int ni = 0; ni < 8; ni++)                                              \
          acc[mi][ni] = __builtin_amdgcn_mfma_f32_16x16x32_bf16(                    \
              a[mi], b[ni], acc[mi][ni], 0, 0, 0);                                  \
      } }

__launch_bounds__(512, 8)
__global__ void gemm_fused_kernel(const ushort_t* __restrict__ f16,
                                  const ushort_t* __restrict__ Wb,
                                  const ushort_t* __restrict__ t16,
                                  float* __restrict__ part) {
    __shared__ ushort_t As[256 * 32];   // 16 KiB
    __shared__ ushort_t Bs[256 * 32];   // 16 KiB
    __shared__ float scratch[256 * 2];  // 34 KiB total -> 4 blocks/CU

    const int tid  = threadIdx.x;
    const int wave = tid >> 6;      // 0..7
    const int lane = tid & 63;
    const int l15  = lane & 15;
    const int lg   = lane >> 4;
    const int m_base = (wave >> 1) * 64;   // 4 m-waves
    const int nh     = wave & 1;           // n half (128 cols)

    // XCD-chunked bijective swizzle (grid 1024), m fastest within each XCD
    // (B slice 16 panels x 256 KB = 4 MiB -> the XCD's private L2).
    const int xcd = blockIdx.x & 7;
    const int idx = blockIdx.x >> 3;          // 0..127
    const int bx  = idx & 7;                  // m chunk (fastest)
    const int by  = xcd * 16 + (idx >> 3);    // n panel 0..127
    const int b0  = bx * 256;
    const int n0  = by * 256;

    // staging: slot s = l*512+tid -> LDS element s*8; row p=s>>2, phys chunk cph=s&3,
    // content chunk cg = cph ^ ((p>>1)&3)  (R10-verified swizzle).
    // B row-permute (R10-verified): phys row p holds n_local = (p&192)|((p&15)<<2)|((p>>4)&3).
    const ushort_t* gA[2];
    const ushort_t* gB[2];
    #pragma unroll
    for (int l = 0; l < 2; l++) {
        int s    = l * 512 + tid;
        int p    = s >> 2;
        int cph  = s & 3;
        int cg   = cph ^ ((p >> 1) & 3);
        int nrot = (p & 192) | ((p & 15) << 2) | ((p >> 4) & 3);
        gA[l] = f16 + (size_t)(b0 + p) * FDIM + cg * 8;
        gB[l] = Wb + (size_t)(n0 + nrot) * FDIM + cg * 8;
    }

    // fragment ds_read offsets; chunk XOR depends only on l15 bits 1..2
    const int cxor = (lg ^ ((l15 >> 1) & 3)) * 8;
    int a_off[4], b_off[8];
    #pragma unroll
    for (int mi = 0; mi < 4; mi++)
        a_off[mi] = (m_base + mi * 16 + l15) * 32 + cxor;
    #pragma unroll
    for (int ni = 0; ni < 8; ni++)
        b_off[ni] = (nh * 128 + ni * 16 + l15) * 32 + cxor;

    f32x4 acc[4][8];
    #pragma unroll
    for (int mi = 0; mi < 4; mi++)
        #pragma unroll
        for (int ni = 0; ni < 8; ni++)
            acc[mi][ni] = (f32x4){0.f, 0.f, 0.f, 0.f};

    // 16 K-steps: stage -> drain -> compute -> WAR barrier.
    #pragma unroll 1
    for (int kt = 0; kt < 16; kt++) {
        STAGE(kt)
        __syncthreads();
        COMPUTE()
        __syncthreads();
    }

    // epilogue: frag ni, col l15 -> n_local = nh*128 + (ni>=4)*64 + l15*4 + (ni&3)
    // -> two ushort4 t16 loads per (mi,r). D row = lg*4 + reg -> b.
    const int c    = n0 >> 9;
    const int half = (n0 >> 8) & 1;
    const int i0   = (n0 & 511) + nh * 128 + l15 * 4;

    #pragma unroll
    for (int mi = 0; mi < 4; mi++) {
        #pragma unroll
        for (int r = 0; r < 4; r++) {
            int b_idx = b0 + m_base + mi * 16 + lg * 4 + r;
            const ushort_t* tp = &t16[(size_t)b_idx * FDIM + i0];
            ushort4 tv0 = *(const ushort4*)tp;
            ushort4 tv1 = *(const ushort4*)(tp + 64);
            float sv = acc[mi][0][r] * bf2f(tv0.x) + acc[mi][1][r] * bf2f(tv0.y)
                     + acc[mi][2][r] * bf2f(tv0.z) + acc[mi][3][r] * bf2f(tv0.w)
                     + acc[mi][4][r] * bf2f(tv1.x) + acc[mi][5][r] * bf2f(tv1.y)
                     + acc[mi][6][r] * bf2f(tv1.z) + acc[mi][7][r] * bf2f(tv1.w);
            sv += __shfl_xor(sv, 1, 64);
            sv += __shfl_xor(sv, 2, 64);
            sv += __shfl_xor(sv, 4, 64);
            sv += __shfl_xor(sv, 8, 64);
            if (l15 == 0)
                scratch[(m_base + mi * 16 + lg * 4 + r) * 2 + nh] = sv;
        }
    }
    __syncthreads();
    if (tid < 256) {
        float v = scratch[tid * 2] + scratch[tid * 2 + 1];
        part[((size_t)(b0 + tid) * CDIM + c) * 2 + half] = v;
    }
}

// ---- MLP head: part[b][c][2] halves -> relu(proj) -> relu(W1) -> W2 ----
__global__ void mlp_kernel(const float* __restrict__ part,
                           const float* __restrict__ b_proj,
                           const float* __restrict__ W1, const float* __restrict__ b1,
                           const float* __restrict__ W2, const float* __restrict__ b2,
                           float* __restrict__ out) {
    __shared__ float h[8][64];
    const int tid = threadIdx.x;
    const int bl  = tid >> 5;        // 0..7
    const int o   = tid & 31;
    const int b   = blockIdx.x * 8 + bl;

    #pragma unroll
    for (int c = o; c < 64; c += 32) {
        float2 v = *(const float2*)&part[((size_t)b * 64 + c) * 2];
        float sv = v.x + v.y + b_proj[c];
        h[bl][c] = sv > 0.f ? sv : 0.f;
    }
    __syncthreads();

    float sv = b1[o];
    #pragma unroll
    for (int c = 0; c < 64; c++) sv += h[bl][c] * W1[o * 64 + c];
    float v = (sv > 0.f ? sv : 0.f) * W2[o];
    v += __shfl_xor(v, 1, 32);
    v += __shfl_xor(v, 2, 32);
    v += __shfl_xor(v, 4, 32);
    v += __shfl_xor(v, 8, 32);
    v += __shfl_xor(v, 16, 32);
    if (o == 0) out[b] = v + b2[0];
}

extern "C" void kernel_launch(void* const* d_in, const int* in_sizes, int n_in,
                              void* d_out, int out_size, void* d_ws, size_t ws_size,
                              hipStream_t stream) {
    const float* t_feat = (const float*)d_in[0];
    const float* f_feat = (const float*)d_in[1];
    const float* W_proj = (const float*)d_in[2];
    const float* b_proj = (const float*)d_in[3];
    const float* W1     = (const float*)d_in[4];
    const float* b1     = (const float*)d_in[5];
    const float* W2     = (const float*)d_in[6];
    const float* b2     = (const float*)d_in[7];
    float* out = (float*)d_out;

    uint8_t* ws = (uint8_t*)d_ws;
    ushort_t* Wb   = (ushort_t*)(ws);                          // 32 MiB
    ushort_t* f16  = (ushort_t*)(ws + 33554432);               // 2 MiB
    ushort_t* t16  = (ushort_t*)(ws + 33554432 + 2097152);     // 2 MiB
    float*    part = (float*)(ws + 33554432 + 2 * 2097152);    // 1 MiB

    convert_all_kernel<<<dim3(9216), dim3(256), 0, stream>>>(W_proj, Wb, f_feat, f16, t_feat, t16);

    gemm_fused_kernel<<<dim3(1024), dim3(512), 0, stream>>>(f16, Wb, t16, part);

    mlp_kernel<<<dim3(BATCH / 8), dim3(256), 0, stream>>>(part, b_proj, W1, b1, W2, b2, out);
}